// Round 11
// baseline (654.446 us; speedup 1.0000x reference)
//
#include <hip/hip_runtime.h>
#include <hip/hip_bf16.h>
#include <hip/hip_fp16.h>
#include <cstdint>

#define F_IN 128
#define F_HID 64
#define NB 64          // nodes per bucket
#define MAXB 2048      // max buckets (N <= 131072)
#define NWG 256        // WGs for hist/fill edge partition

typedef _Float16 half8 __attribute__((ext_vector_type(8)));
typedef float floatx4 __attribute__((ext_vector_type(4)));

__device__ __forceinline__ float bf2f(unsigned short u) {
  return __uint_as_float(((unsigned int)u) << 16);
}
__device__ __forceinline__ unsigned short f2bf(float f) {
  unsigned int u = __float_as_uint(f);
  u += 0x7FFFu + ((u >> 16) & 1u);   // round-to-nearest-even
  return (unsigned short)(u >> 16);
}
__device__ __forceinline__ float h2f(unsigned short u) {
  return __half2float(__ushort_as_half(u));
}
__device__ __forceinline__ unsigned short f2h(float f) {
  return __half_as_ushort(__float2half(f));
}

// ---------------- dtype detection (resolved bf16 on this dataset) ----------------
__global__ __launch_bounds__(64) void k_detect(const unsigned int* __restrict__ Xw,
                                               int* __restrict__ flag) {
  int lane = threadIdx.x;
  int cnt = 0;
  for (int t = lane; t < 256; t += 64) {
    unsigned int ex = (Xw[t] >> 7) & 0xFFu;
    cnt += (ex >= 117u && ex <= 137u) ? 1 : 0;
  }
#pragma unroll
  for (int off = 32; off > 0; off >>= 1) cnt += __shfl_xor(cnt, off, 64);
  if (lane == 0) *flag = (cnt >= 128) ? 1 : 0;  // 1 = bf16, 0 = fp32
}

// ---------------- weight prep: fragment-order fp16 copies in ws ----------------
// B-frag for mfma_f32_16x16x32_f16: B[k=(lane>>4)*8+j][n=lane&15].
// frag-order dest (ushorts) for W element (k,n), 64 cols:
//   c=k>>5, q=(k>>3)&3, j=k&7, t=n>>4, m=n&15 -> ((c*4+t)*64 + q*16+m)*8 + j
// Each lane's fragment is then 16 contiguous bytes; lane-stride 16 B = coalesced.
__global__ __launch_bounds__(256) void k_prep(const void* __restrict__ W1v,
                                              const void* __restrict__ W2v,
                                              const void* __restrict__ fc1Wv,
                                              unsigned short* __restrict__ fW1,
                                              unsigned short* __restrict__ fW2,
                                              unsigned short* __restrict__ fPR,
                                              const int* __restrict__ flagp) {
  const bool isb = (*flagp != 0);
  int tid = blockIdx.x * 256 + threadIdx.x;
  int stride = gridDim.x * 256;
  // W1: 128 x 64
  for (int e = tid; e < F_IN * F_HID; e += stride) {
    int k = e >> 6, n = e & 63;
    unsigned short v = isb ? f2h(bf2f(((const unsigned short*)W1v)[e]))
                           : f2h(((const float*)W1v)[e]);
    int c = k >> 5, q = (k >> 3) & 3, j = k & 7, t = n >> 4, m = n & 15;
    fW1[((c * 4 + t) * 64 + q * 16 + m) * 8 + j] = v;
  }
  // W2: 64 x 64
  for (int e = tid; e < F_HID * F_HID; e += stride) {
    int k = e >> 6, n = e & 63;
    unsigned short v = isb ? f2h(bf2f(((const unsigned short*)W2v)[e]))
                           : f2h(((const float*)W2v)[e]);
    int c = k >> 5, q = (k >> 3) & 3, j = k & 7, t = n >> 4, m = n & 15;
    fW2[((c * 4 + t) * 64 + q * 16 + m) * 8 + j] = v;
  }
  // fc1W: 4 slices g: rows (g&2 ? 64:0)+k, cols (g&1)*64 + n  (64 x 64 each)
  for (int ge = tid; ge < 4 * F_HID * 64; ge += stride) {
    int g = ge >> 12, e = ge & 4095;
    int k = e >> 6, n = e & 63;
    int src = (((g & 2) ? 64 : 0) + k) * 128 + (g & 1) * 64 + n;
    unsigned short v = isb ? f2h(bf2f(((const unsigned short*)fc1Wv)[src]))
                           : f2h(((const float*)fc1Wv)[src]);
    int c = k >> 5, q = (k >> 3) & 3, j = k & 7, t = n >> 4, m = n & 15;
    fPR[g * 4096 + ((c * 4 + t) * 64 + q * 16 + m) * 8 + j] = v;
  }
}

// ---------------- bucket build (no global atomics) ----------------
__global__ __launch_bounds__(256) void k_bhist(const int* __restrict__ dst,
                                               int* __restrict__ hist,
                                               int E, int B, int chunk) {
  __shared__ int lh[MAXB];
  int w = blockIdx.x, tid = threadIdx.x;
  for (int b = tid; b < B; b += 256) lh[b] = 0;
  __syncthreads();
  int e0 = w * chunk, e1 = min(E, e0 + chunk);
  for (int e = e0 + tid; e < e1; e += 256) atomicAdd(&lh[dst[e] >> 6], 1);
  __syncthreads();
  for (int b = tid; b < B; b += 256) hist[w * B + b] = lh[b];
}

__global__ __launch_bounds__(256) void k_bscan1(int* __restrict__ hist,
                                                int* __restrict__ btot, int B) {
  int b = blockIdx.x * 256 + threadIdx.x;
  if (b >= B) return;
  int acc = 0;
  for (int w = 0; w < NWG; w++) {
    int idx = w * B + b;
    int v = hist[idx];
    hist[idx] = acc;
    acc += v;
  }
  btot[b] = acc;
}

__global__ __launch_bounds__(256) void k_bscan2(const int* __restrict__ btot,
                                                int* __restrict__ boff, int B, int E) {
  __shared__ int partial[256];
  int t = threadIdx.x;
  int CH = (B + 255) / 256;
  int b0 = t * CH, b1 = min(B, b0 + CH);
  int tt = 0;
  for (int b = b0; b < b1; b++) tt += btot[b];
  partial[t] = tt;
  __syncthreads();
  if (t == 0) {
    int acc = 0;
    for (int i = 0; i < 256; i++) { int v = partial[i]; partial[i] = acc; acc += v; }
  }
  __syncthreads();
  int off = partial[t];
  for (int b = b0; b < b1; b++) { boff[b] = off; off += btot[b]; }
  if (t == 255) boff[B] = E;
}

// record = (dst_local << 17) | src   (needs N <= 131072)
__global__ __launch_bounds__(256) void k_bfill(const int* __restrict__ src,
                                               const int* __restrict__ dst,
                                               const int* __restrict__ hist,
                                               const int* __restrict__ boff,
                                               int* __restrict__ buck,
                                               int E, int B, int chunk) {
  __shared__ int cur[MAXB];
  int w = blockIdx.x, tid = threadIdx.x;
  for (int b = tid; b < B; b += 256) cur[b] = boff[b] + hist[w * B + b];
  __syncthreads();
  int e0 = w * chunk, e1 = min(E, e0 + chunk);
  for (int e = e0 + tid; e < e1; e += 256) {
    int d = dst[e];
    int b = d >> 6, dl = d & 63;
    int p = atomicAdd(&cur[b], 1);
    buck[p] = (dl << 17) | src[e];
  }
}

// ---------------- per-bucket counting sort -> exact per-node CSR ----------------
__global__ __launch_bounds__(256) void k_bsort(const int* __restrict__ buck,
                                               const int* __restrict__ boff,
                                               int* __restrict__ csr,
                                               int* __restrict__ noff,
                                               float* __restrict__ dinv, int N) {
  __shared__ int bin[NB];
  __shared__ int excl[NB];
  int b = blockIdx.x, tid = threadIdx.x;
  if (tid < NB) bin[tid] = 0;
  __syncthreads();
  int r0 = boff[b], r1 = boff[b + 1];
  for (int r = r0 + tid; r < r1; r += 256) atomicAdd(&bin[buck[r] >> 17], 1);
  __syncthreads();
  if (tid == 0) {
    int acc = 0;
    for (int i = 0; i < NB; i++) { excl[i] = acc; acc += bin[i]; }
  }
  __syncthreads();
  if (tid < NB) {
    int n = b * NB + tid;
    if (n < N) {
      dinv[n] = rsqrtf((float)bin[tid] + 1.0f);  // +1 self-loop
      noff[n] = r0 + excl[tid];
    }
  }
  if (b == gridDim.x - 1 && tid == 128) noff[N] = r1;  // r1 == E for last bucket
  __syncthreads();
  if (tid < NB) bin[tid] = excl[tid];  // reuse as cursors
  __syncthreads();
  for (int r = r0 + tid; r < r1; r += 256) {
    int rec = buck[r];
    int p = atomicAdd(&bin[rec >> 17], 1);
    csr[r0 + p] = rec & 0x1FFFF;
  }
}

// ============ MFMA GEMMs: no LDS, frag-order weights from global (L2 broadcast), ============
// ============ multi-tile per wave with next-tile A-prefetch pipeline              ============
// A-frag:  A[m = lane&15][k = (lane>>4)*8 + j]
// D:       D[row = (lane>>4)*4 + reg][col = lane&15]

// ---------------- GEMM1: G = fp16((X @ W1) * dinv[row]), X bf16 (MFMA) or fp32 (VALU) ----
__device__ __forceinline__ void gemm1_valu(const float* __restrict__ Xf,
                                           const float* __restrict__ Wf,
                                           const float* __restrict__ dinv,
                                           unsigned short* __restrict__ A, int N,
                                           int lane, int wave) {
  const int RPW = 8;
  for (int r0 = (blockIdx.x * 4 + wave) * RPW; r0 < N; r0 += gridDim.x * 4 * RPW) {
    float acc[RPW];
#pragma unroll
    for (int r = 0; r < RPW; r++) acc[r] = 0.f;
#pragma unroll 1
    for (int k4 = 0; k4 < F_IN / 4; ++k4) {
      float w0 = Wf[(k4 * 4 + 0) * F_HID + lane];  // L2-resident broadcast
      float w1 = Wf[(k4 * 4 + 1) * F_HID + lane];
      float w2 = Wf[(k4 * 4 + 2) * F_HID + lane];
      float w3 = Wf[(k4 * 4 + 3) * F_HID + lane];
#pragma unroll
      for (int r = 0; r < RPW; r++) {
        int rr = r0 + r; rr = rr < N ? rr : N - 1;
        float4 xv = *reinterpret_cast<const float4*>(Xf + (size_t)rr * F_IN + k4 * 4);
        acc[r] += xv.x * w0 + xv.y * w1 + xv.z * w2 + xv.w * w3;
      }
    }
#pragma unroll
    for (int r = 0; r < RPW; r++) {
      int rr = r0 + r;
      if (rr < N) A[(size_t)rr * F_HID + lane] = f2h(acc[r] * dinv[rr]);
    }
  }
}

__global__ __launch_bounds__(256, 4) void k_gemm1(const void* __restrict__ Xv,
                                                  const unsigned short* __restrict__ fW1,
                                                  const void* __restrict__ Wv,
                                                  const float* __restrict__ dinv,
                                                  unsigned short* __restrict__ G, int N,
                                                  const int* __restrict__ flagp) {
  const bool isb = (*flagp != 0);
  int tid = threadIdx.x;
  const int lane = tid & 63, wave = tid >> 6;
  if (!isb) { gemm1_valu((const float*)Xv, (const float*)Wv, dinv, G, N, lane, wave); return; }

  const unsigned short* X = (const unsigned short*)Xv;
  const int m = lane & 15, q = lane >> 4;
  half8 bfrag[4][4];
#pragma unroll
  for (int c = 0; c < 4; c++)
#pragma unroll
    for (int t = 0; t < 4; t++)
      bfrag[c][t] = *reinterpret_cast<const half8*>(fW1 + ((c * 4 + t) * 64 + lane) * 8);

  int ntiles = (N + 15) >> 4;
  int stride = gridDim.x * 4;
  int tile = blockIdx.x * 4 + wave;
  if (tile >= ntiles) return;
  int rm = (tile << 4) + m; rm = rm < N ? rm : N - 1;
  const uint4* xr = reinterpret_cast<const uint4*>(X + (size_t)rm * F_IN);
  uint4 cur[4] = {xr[q], xr[4 + q], xr[8 + q], xr[12 + q]};
  for (;;) {
    int nt = tile + stride;
    bool has = nt < ntiles;
    uint4 nxt[4];
    if (has) {
      int rm2 = (nt << 4) + m; rm2 = rm2 < N ? rm2 : N - 1;
      const uint4* xr2 = reinterpret_cast<const uint4*>(X + (size_t)rm2 * F_IN);
      nxt[0] = xr2[q]; nxt[1] = xr2[4 + q]; nxt[2] = xr2[8 + q]; nxt[3] = xr2[12 + q];
    }
    floatx4 acc[4] = {{0.f,0.f,0.f,0.f},{0.f,0.f,0.f,0.f},{0.f,0.f,0.f,0.f},{0.f,0.f,0.f,0.f}};
#pragma unroll
    for (int c = 0; c < 4; c++) {
      uint4 d = cur[c];
      half8 a;
      a[0] = (_Float16)__uint_as_float(d.x << 16);
      a[1] = (_Float16)__uint_as_float(d.x & 0xFFFF0000u);
      a[2] = (_Float16)__uint_as_float(d.y << 16);
      a[3] = (_Float16)__uint_as_float(d.y & 0xFFFF0000u);
      a[4] = (_Float16)__uint_as_float(d.z << 16);
      a[5] = (_Float16)__uint_as_float(d.z & 0xFFFF0000u);
      a[6] = (_Float16)__uint_as_float(d.w << 16);
      a[7] = (_Float16)__uint_as_float(d.w & 0xFFFF0000u);
#pragma unroll
      for (int t = 0; t < 4; t++)
        acc[t] = __builtin_amdgcn_mfma_f32_16x16x32_f16(a, bfrag[c][t], acc[t], 0, 0, 0);
    }
    int r0 = tile << 4;
#pragma unroll
    for (int rr = 0; rr < 4; rr++) {
      int grow = r0 + q * 4 + rr;
      if (grow < N) {
        float dv = dinv[grow];
#pragma unroll
        for (int t = 0; t < 4; t++)
          G[(size_t)grow * F_HID + t * 16 + m] = f2h(acc[t][rr] * dv);
      }
    }
    if (!has) break;
    cur[0] = nxt[0]; cur[1] = nxt[1]; cur[2] = nxt[2]; cur[3] = nxt[3];
    tile = nt;
  }
}

// ---------------- GEMM2: G = fp16((O @ W2) * dinv[row])   (O fp16, MFMA) ----------------
__global__ __launch_bounds__(256, 4) void k_gemm2(const unsigned short* __restrict__ O,
                                                  const unsigned short* __restrict__ fW2,
                                                  const float* __restrict__ dinv,
                                                  unsigned short* __restrict__ G, int N) {
  int tid = threadIdx.x;
  const int lane = tid & 63, wave = tid >> 6;
  const int m = lane & 15, q = lane >> 4;
  half8 bfrag[2][4];
#pragma unroll
  for (int c = 0; c < 2; c++)
#pragma unroll
    for (int t = 0; t < 4; t++)
      bfrag[c][t] = *reinterpret_cast<const half8*>(fW2 + ((c * 4 + t) * 64 + lane) * 8);

  int ntiles = (N + 15) >> 4;
  int stride = gridDim.x * 4;
  int tile = blockIdx.x * 4 + wave;
  if (tile >= ntiles) return;
  int rm = (tile << 4) + m; rm = rm < N ? rm : N - 1;
  half8 cur[2] = {
    *reinterpret_cast<const half8*>(O + (size_t)rm * F_HID + q * 8),
    *reinterpret_cast<const half8*>(O + (size_t)rm * F_HID + 32 + q * 8)};
  for (;;) {
    int nt = tile + stride;
    bool has = nt < ntiles;
    half8 nxt[2];
    if (has) {
      int rm2 = (nt << 4) + m; rm2 = rm2 < N ? rm2 : N - 1;
      nxt[0] = *reinterpret_cast<const half8*>(O + (size_t)rm2 * F_HID + q * 8);
      nxt[1] = *reinterpret_cast<const half8*>(O + (size_t)rm2 * F_HID + 32 + q * 8);
    }
    floatx4 acc[4] = {{0.f,0.f,0.f,0.f},{0.f,0.f,0.f,0.f},{0.f,0.f,0.f,0.f},{0.f,0.f,0.f,0.f}};
#pragma unroll
    for (int c = 0; c < 2; c++)
#pragma unroll
      for (int t = 0; t < 4; t++)
        acc[t] = __builtin_amdgcn_mfma_f32_16x16x32_f16(cur[c], bfrag[c][t], acc[t], 0, 0, 0);
    int r0 = tile << 4;
#pragma unroll
    for (int rr = 0; rr < 4; rr++) {
      int grow = r0 + q * 4 + rr;
      if (grow < N) {
        float dv = dinv[grow];
#pragma unroll
        for (int t = 0; t < 4; t++)
          G[(size_t)grow * F_HID + t * 16 + m] = f2h(acc[t][rr] * dv);
      }
    }
    if (!has) break;
    cur[0] = nxt[0]; cur[1] = nxt[1];
    tile = nt;
  }
}

// ---------------- aggregate (exact CSR, register accumulation, fp16 rows) + fused epilogue ----------------
template <bool RELU>
__global__ __launch_bounds__(256) void k_agg(const int* __restrict__ csr,
                                             const int* __restrict__ noff,
                                             const unsigned short* __restrict__ H,
                                             const float* __restrict__ dinv,
                                             const void* __restrict__ bias,
                                             unsigned short* __restrict__ OUT, int N,
                                             const int* __restrict__ flagp) {
  const bool isb = (*flagp != 0);
  int lane = threadIdx.x & 63;
  int gw = (blockIdx.x * 256 + threadIdx.x) >> 6;
  int nW = (gridDim.x * 256) >> 6;
  float bv = isb ? bf2f(((const unsigned short*)bias)[lane])
                 : ((const float*)bias)[lane];
  for (int n = gw; n < N; n += nW) {
    int start = noff[n], end = noff[n + 1];
    float acc0 = 0.f, acc1 = 0.f;
    for (int e0 = start; e0 < end; e0 += 64) {
      int ee = e0 + lane;
      int idx = (ee < end) ? csr[ee] : 0;
      int m = end - e0; m = m < 64 ? m : 64;
      int k = 0;
      for (; k + 3 < m; k += 4) {
        int s0 = __shfl(idx, k, 64);
        int s1 = __shfl(idx, k + 1, 64);
        int s2 = __shfl(idx, k + 2, 64);
        int s3 = __shfl(idx, k + 3, 64);
        float v0 = h2f(H[(size_t)s0 * F_HID + lane]);
        float v1 = h2f(H[(size_t)s1 * F_HID + lane]);
        float v2 = h2f(H[(size_t)s2 * F_HID + lane]);
        float v3 = h2f(H[(size_t)s3 * F_HID + lane]);
        acc0 += v0 + v2;
        acc1 += v1 + v3;
      }
      for (; k < m; k++) {
        int s0 = __shfl(idx, k, 64);
        acc0 += h2f(H[(size_t)s0 * F_HID + lane]);
      }
    }
    float self = h2f(H[(size_t)n * F_HID + lane]);  // self-loop (already * dinv[n])
    float o = (acc0 + acc1 + self) * dinv[n] + bv;
    if (RELU) o = fmaxf(o, 0.f);
    OUT[(size_t)n * F_HID + lane] = f2h(o);
  }
}

// ---------------- PR GEMM (MFMA): PR[n][0:128]=O[n]@Wa ; [128:256]=O[n]@Wb, fp16 out ----
// Block handles output-column group g = blockIdx&3 (64 cols); weights from fPR[g].
__global__ __launch_bounds__(256, 4) void k_gemm_pr(const unsigned short* __restrict__ O,
                                                    const unsigned short* __restrict__ fPR,
                                                    unsigned short* __restrict__ PR, int N) {
  const int g = blockIdx.x & 3;
  int tid = threadIdx.x;
  const int lane = tid & 63, wave = tid >> 6;
  const int m = lane & 15, q = lane >> 4;
  const unsigned short* fW = fPR + g * 4096;
  half8 bfrag[2][4];
#pragma unroll
  for (int c = 0; c < 2; c++)
#pragma unroll
    for (int t = 0; t < 4; t++)
      bfrag[c][t] = *reinterpret_cast<const half8*>(fW + ((c * 4 + t) * 64 + lane) * 8);

  int ntiles = (N + 15) >> 4;
  int stride = (gridDim.x >> 2) * 4;
  int tile = (blockIdx.x >> 2) * 4 + wave;
  if (tile >= ntiles) return;
  int rm = (tile << 4) + m; rm = rm < N ? rm : N - 1;
  half8 cur[2] = {
    *reinterpret_cast<const half8*>(O + (size_t)rm * F_HID + q * 8),
    *reinterpret_cast<const half8*>(O + (size_t)rm * F_HID + 32 + q * 8)};
  for (;;) {
    int nt = tile + stride;
    bool has = nt < ntiles;
    half8 nxt[2];
    if (has) {
      int rm2 = (nt << 4) + m; rm2 = rm2 < N ? rm2 : N - 1;
      nxt[0] = *reinterpret_cast<const half8*>(O + (size_t)rm2 * F_HID + q * 8);
      nxt[1] = *reinterpret_cast<const half8*>(O + (size_t)rm2 * F_HID + 32 + q * 8);
    }
    floatx4 acc[4] = {{0.f,0.f,0.f,0.f},{0.f,0.f,0.f,0.f},{0.f,0.f,0.f,0.f},{0.f,0.f,0.f,0.f}};
#pragma unroll
    for (int c = 0; c < 2; c++)
#pragma unroll
      for (int t = 0; t < 4; t++)
        acc[t] = __builtin_amdgcn_mfma_f32_16x16x32_f16(cur[c], bfrag[c][t], acc[t], 0, 0, 0);
    int r0 = tile << 4;
#pragma unroll
    for (int rr = 0; rr < 4; rr++) {
      int grow = r0 + q * 4 + rr;
      if (grow < N) {
#pragma unroll
        for (int t = 0; t < 4; t++)
          PR[(size_t)grow * 256 + g * 64 + t * 16 + m] = f2h(acc[t][rr]);
      }
    }
    if (!has) break;
    cur[0] = nxt[0]; cur[1] = nxt[1];
    tile = nt;
  }
}

// ---------------- query: out[q] = relu(P[i[q]] + R[j[q]] + fc1_b) @ fc2_W + fc2_b ----------------
__global__ __launch_bounds__(256) void k_query(const unsigned short* __restrict__ PRu,
                                               const int* __restrict__ qi,
                                               const int* __restrict__ qj,
                                               const void* __restrict__ fc1b,
                                               const void* __restrict__ fc2W,
                                               const void* __restrict__ fc2b,
                                               void* __restrict__ out, int Q,
                                               const int* __restrict__ flagp) {
  const bool isb = (*flagp != 0);
  int tid = threadIdx.x;
  int lane = tid & 63;
  int wave = tid >> 6;
  int g = lane >> 4, m = lane & 15;
  float bb[8], w0[8], w1[8];
#pragma unroll
  for (int t = 0; t < 8; t++) {
    int h = m * 8 + t;
    if (isb) {
      bb[t] = bf2f(((const unsigned short*)fc1b)[h]);
      w0[t] = bf2f(((const unsigned short*)fc2W)[h * 2 + 0]);
      w1[t] = bf2f(((const unsigned short*)fc2W)[h * 2 + 1]);
    } else {
      bb[t] = ((const float*)fc1b)[h];
      w0[t] = ((const float*)fc2W)[h * 2 + 0];
      w1[t] = ((const float*)fc2W)[h * 2 + 1];
    }
  }
  float ob0 = isb ? bf2f(((const unsigned short*)fc2b)[0]) : ((const float*)fc2b)[0];
  float ob1 = isb ? bf2f(((const unsigned short*)fc2b)[1]) : ((const float*)fc2b)[1];
  int gw = blockIdx.x * 4 + wave;
  int nW = gridDim.x * 4;
  int nQuad = (Q + 3) >> 2;
  for (int quad = gw; quad < nQuad; quad += nW) {
    int q = quad * 4 + g;
    int qq = q < Q ? q : Q - 1;
    int iq = qi[qq], jq = qj[qq];
    const ushort4* Pr = reinterpret_cast<const ushort4*>(PRu + (size_t)iq * 256) + m * 2;
    const ushort4* Rr = reinterpret_cast<const ushort4*>(PRu + (size_t)jq * 256 + 128) + m * 2;
    ushort4 pa = Pr[0], pb = Pr[1];
    ushort4 ra = Rr[0], rb = Rr[1];
    float h[8] = {h2f(pa.x) + h2f(ra.x), h2f(pa.y) + h2f(ra.y),
                  h2f(pa.z) + h2f(ra.z), h2f(pa.w) + h2f(ra.w),
                  h2f(pb.x) + h2f(rb.x), h2f(pb.y) + h2f(rb.y),
                  h2f(pb.z) + h2f(rb.z), h2f(pb.w) + h2f(rb.w)};
    float r0 = 0.f, r1 = 0.f;
#pragma unroll
    for (int t = 0; t < 8; t++) {
      float hv = fmaxf(h[t] + bb[t], 0.f);
      r0 += hv * w0[t];
      r1 += hv * w1[t];
    }
#pragma unroll
    for (int off = 8; off > 0; off >>= 1) {
      r0 += __shfl_xor(r0, off, 16);
      r1 += __shfl_xor(r1, off, 16);
    }
    if (m == 0 && q < Q) {
      if (isb) {
        *reinterpret_cast<ushort2*>((unsigned short*)out + (size_t)q * 2) =
            make_ushort2(f2bf(r0 + ob0), f2bf(r1 + ob1));
      } else {
        *reinterpret_cast<float2*>((float*)out + (size_t)q * 2) =
            make_float2(r0 + ob0, r1 + ob1);
      }
    }
  }
}

extern "C" void kernel_launch(void* const* d_in, const int* in_sizes, int n_in,
                              void* d_out, int out_size, void* d_ws, size_t ws_size,
                              hipStream_t stream) {
  const void* X    = d_in[0];
  const int*  edges= (const int*)d_in[1];
  const int*  qi   = (const int*)d_in[2];
  const int*  qj   = (const int*)d_in[3];
  const void* W1   = d_in[4];
  const void* b1   = d_in[5];
  const void* W2   = d_in[6];
  const void* b2   = d_in[7];
  const void* fc1W = d_in[8];
  const void* fc1b = d_in[9];
  const void* fc2W = d_in[10];
  const void* fc2b = d_in[11];

  const int N = in_sizes[0] / F_IN;
  const int E = in_sizes[1] / 2;
  const int Q = in_sizes[2];
  const int B = (N + NB - 1) / NB;           // buckets (<= MAXB for N <= 131072)
  const int chunk = (E + NWG - 1) / NWG;

  char* ws = (char*)d_ws;
  size_t off = 0;
  auto alloc = [&](size_t bytes) -> void* {
    void* p = ws + off;
    off += (bytes + 255) & ~(size_t)255;
    return p;
  };
  int*            flag = (int*)alloc(4);
  float*          dinv = (float*)alloc((size_t)N * 4);
  unsigned short* G    = (unsigned short*)alloc((size_t)N * F_HID * 2);  // gemm out (fp16)
  unsigned short* O    = (unsigned short*)alloc((size_t)N * F_HID * 2);  // layer out (fp16)
  unsigned short* fW1  = (unsigned short*)alloc((size_t)F_IN * F_HID * 2);   // frag-order fp16
  unsigned short* fW2  = (unsigned short*)alloc((size_t)F_HID * F_HID * 2);
  unsigned short* fPR  = (unsigned short*)alloc((size_t)4 * F_HID * 64 * 2);
  unsigned short* PR   = (unsigned short*)alloc((size_t)N * 256 * 2);    // [P | R] fp16
  // bucket/CSR scratch aliases PR (all reads precede gemm_pr's PR writes)
  char* scr = (char*)PR;
  size_t soff = 0;
  auto salloc = [&](size_t bytes) -> void* {
    void* p = scr + soff;
    soff += (bytes + 255) & ~(size_t)255;
    return p;
  };
  int* hist = (int*)salloc((size_t)NWG * B * 4);
  int* btot = (int*)salloc((size_t)(B + 1) * 4);
  int* boff = (int*)salloc((size_t)(B + 1) * 4);
  int* buck = (int*)salloc((size_t)E * 4);
  int* csr  = (int*)salloc((size_t)E * 4);
  int* noff = (int*)salloc((size_t)(N + 1) * 4);
  (void)ws_size; (void)n_in; (void)out_size;

  const int* esrc = edges;
  const int* edst = edges + E;

  k_detect<<<1, 64, 0, stream>>>((const unsigned int*)X, flag);
  k_prep<<<16, 256, 0, stream>>>(W1, W2, fc1W, fW1, fW2, fPR, flag);

  // bucket build + per-bucket counting sort -> exact CSR + noff + dinv
  k_bhist<<<NWG, 256, 0, stream>>>(edst, hist, E, B, chunk);
  k_bscan1<<<(B + 255) / 256, 256, 0, stream>>>(hist, btot, B);
  k_bscan2<<<1, 256, 0, stream>>>(btot, boff, B, E);
  k_bfill<<<NWG, 256, 0, stream>>>(esrc, edst, hist, boff, buck, E, B, chunk);
  k_bsort<<<B, 256, 0, stream>>>(buck, boff, csr, noff, dinv, N);

  // layer 1
  k_gemm1<<<512, 256, 0, stream>>>(X, fW1, W1, dinv, G, N, flag);
  k_agg<true><<<2048, 256, 0, stream>>>(csr, noff, G, dinv, b1, O, N, flag);

  // layer 2
  k_gemm2<<<512, 256, 0, stream>>>(O, fW2, dinv, G, N);
  k_agg<false><<<2048, 256, 0, stream>>>(csr, noff, G, dinv, b2, O, N, flag);

  // MLP factorization: PR = out2 @ [Wa | Wb]  (overwrites bucket scratch — safe)
  k_gemm_pr<<<512, 256, 0, stream>>>(O, fPR, PR, N);

  // per-query: gather P[i] + R[j], relu, fc2
  k_query<<<4096, 256, 0, stream>>>(PR, qi, qj, fc1b, fc2W, fc2b, d_out, Q, flag);
}

// Round 12
// 563.160 us; speedup vs baseline: 1.1621x; 1.1621x over previous
//
#include <hip/hip_runtime.h>
#include <hip/hip_bf16.h>
#include <hip/hip_fp16.h>
#include <cstdint>

#define F_IN 128
#define F_HID 64
#define NB 64          // nodes per bucket
#define MAXB 2048      // max buckets (N <= 131072)
#define NWG 256        // WGs for hist/fill edge partition

typedef _Float16 half8 __attribute__((ext_vector_type(8)));
typedef float floatx4 __attribute__((ext_vector_type(4)));

__device__ __forceinline__ float bf2f(unsigned short u) {
  return __uint_as_float(((unsigned int)u) << 16);
}
__device__ __forceinline__ unsigned short f2bf(float f) {
  unsigned int u = __float_as_uint(f);
  u += 0x7FFFu + ((u >> 16) & 1u);   // round-to-nearest-even
  return (unsigned short)(u >> 16);
}
__device__ __forceinline__ float h2f(unsigned short u) {
  return __half2float(__ushort_as_half(u));
}
__device__ __forceinline__ unsigned short f2h(float f) {
  return __half_as_ushort(__float2half(f));
}

// ---------------- dtype detection (resolved bf16 on this dataset) ----------------
__global__ __launch_bounds__(64) void k_detect(const unsigned int* __restrict__ Xw,
                                               int* __restrict__ flag) {
  int lane = threadIdx.x;
  int cnt = 0;
  for (int t = lane; t < 256; t += 64) {
    unsigned int ex = (Xw[t] >> 7) & 0xFFu;
    cnt += (ex >= 117u && ex <= 137u) ? 1 : 0;
  }
#pragma unroll
  for (int off = 32; off > 0; off >>= 1) cnt += __shfl_xor(cnt, off, 64);
  if (lane == 0) *flag = (cnt >= 128) ? 1 : 0;  // 1 = bf16, 0 = fp32
}

// ---------------- X cast: lane-linear streaming bf16/fp32 -> fp16 ----------------
// Pure m13-style copy pattern (proven 6.3 TB/s). Diagnostic + traffic halver:
// if THIS kernel also crawls at ~300 GB/s, the gemm1 wall is X/memory-state,
// not kernel structure.
__global__ __launch_bounds__(256) void k_xcast(const void* __restrict__ Xv,
                                               unsigned short* __restrict__ Xh,
                                               int total8, const int* __restrict__ flagp) {
  const bool isb = (*flagp != 0);
  int t = blockIdx.x * 256 + threadIdx.x;
  int stride = gridDim.x * 256;
  for (; t < total8; t += stride) {
    unsigned short r[8];
    if (isb) {
      uint4 d = reinterpret_cast<const uint4*>(Xv)[t];  // 8 bf16
      r[0] = f2h(__uint_as_float(d.x << 16));
      r[1] = f2h(__uint_as_float(d.x & 0xFFFF0000u));
      r[2] = f2h(__uint_as_float(d.y << 16));
      r[3] = f2h(__uint_as_float(d.y & 0xFFFF0000u));
      r[4] = f2h(__uint_as_float(d.z << 16));
      r[5] = f2h(__uint_as_float(d.z & 0xFFFF0000u));
      r[6] = f2h(__uint_as_float(d.w << 16));
      r[7] = f2h(__uint_as_float(d.w & 0xFFFF0000u));
    } else {
      float4 a = reinterpret_cast<const float4*>(Xv)[2 * t];
      float4 b = reinterpret_cast<const float4*>(Xv)[2 * t + 1];
      r[0] = f2h(a.x); r[1] = f2h(a.y); r[2] = f2h(a.z); r[3] = f2h(a.w);
      r[4] = f2h(b.x); r[5] = f2h(b.y); r[6] = f2h(b.z); r[7] = f2h(b.w);
    }
    uint4 o;
    o.x = (unsigned int)r[0] | ((unsigned int)r[1] << 16);
    o.y = (unsigned int)r[2] | ((unsigned int)r[3] << 16);
    o.z = (unsigned int)r[4] | ((unsigned int)r[5] << 16);
    o.w = (unsigned int)r[6] | ((unsigned int)r[7] << 16);
    reinterpret_cast<uint4*>(Xh)[t] = o;
  }
}

// ---------------- weight prep: fragment-order fp16 copies in ws ----------------
// B-frag for mfma_f32_16x16x32_f16: B[k=(lane>>4)*8+j][n=lane&15].
// frag-order dest (ushorts) for W element (k,n), 64 cols:
//   c=k>>5, q=(k>>3)&3, j=k&7, t=n>>4, m=n&15 -> ((c*4+t)*64 + q*16+m)*8 + j
__global__ __launch_bounds__(256) void k_prep(const void* __restrict__ W1v,
                                              const void* __restrict__ W2v,
                                              const void* __restrict__ fc1Wv,
                                              unsigned short* __restrict__ fW1,
                                              unsigned short* __restrict__ fW2,
                                              unsigned short* __restrict__ fPR,
                                              const int* __restrict__ flagp) {
  const bool isb = (*flagp != 0);
  int tid = blockIdx.x * 256 + threadIdx.x;
  int stride = gridDim.x * 256;
  for (int e = tid; e < F_IN * F_HID; e += stride) {
    int k = e >> 6, n = e & 63;
    unsigned short v = isb ? f2h(bf2f(((const unsigned short*)W1v)[e]))
                           : f2h(((const float*)W1v)[e]);
    int c = k >> 5, q = (k >> 3) & 3, j = k & 7, t = n >> 4, m = n & 15;
    fW1[((c * 4 + t) * 64 + q * 16 + m) * 8 + j] = v;
  }
  for (int e = tid; e < F_HID * F_HID; e += stride) {
    int k = e >> 6, n = e & 63;
    unsigned short v = isb ? f2h(bf2f(((const unsigned short*)W2v)[e]))
                           : f2h(((const float*)W2v)[e]);
    int c = k >> 5, q = (k >> 3) & 3, j = k & 7, t = n >> 4, m = n & 15;
    fW2[((c * 4 + t) * 64 + q * 16 + m) * 8 + j] = v;
  }
  for (int ge = tid; ge < 4 * F_HID * 64; ge += stride) {
    int g = ge >> 12, e = ge & 4095;
    int k = e >> 6, n = e & 63;
    int src = (((g & 2) ? 64 : 0) + k) * 128 + (g & 1) * 64 + n;
    unsigned short v = isb ? f2h(bf2f(((const unsigned short*)fc1Wv)[src]))
                           : f2h(((const float*)fc1Wv)[src]);
    int c = k >> 5, q = (k >> 3) & 3, j = k & 7, t = n >> 4, m = n & 15;
    fPR[g * 4096 + ((c * 4 + t) * 64 + q * 16 + m) * 8 + j] = v;
  }
}

// ---------------- bucket build (no global atomics) ----------------
__global__ __launch_bounds__(256) void k_bhist(const int* __restrict__ dst,
                                               int* __restrict__ hist,
                                               int E, int B, int chunk) {
  __shared__ int lh[MAXB];
  int w = blockIdx.x, tid = threadIdx.x;
  for (int b = tid; b < B; b += 256) lh[b] = 0;
  __syncthreads();
  int e0 = w * chunk, e1 = min(E, e0 + chunk);
  for (int e = e0 + tid; e < e1; e += 256) atomicAdd(&lh[dst[e] >> 6], 1);
  __syncthreads();
  for (int b = tid; b < B; b += 256) hist[w * B + b] = lh[b];
}

__global__ __launch_bounds__(256) void k_bscan1(int* __restrict__ hist,
                                                int* __restrict__ btot, int B) {
  int b = blockIdx.x * 256 + threadIdx.x;
  if (b >= B) return;
  int acc = 0;
  for (int w = 0; w < NWG; w++) {
    int idx = w * B + b;
    int v = hist[idx];
    hist[idx] = acc;
    acc += v;
  }
  btot[b] = acc;
}

__global__ __launch_bounds__(256) void k_bscan2(const int* __restrict__ btot,
                                                int* __restrict__ boff, int B, int E) {
  __shared__ int partial[256];
  int t = threadIdx.x;
  int CH = (B + 255) / 256;
  int b0 = t * CH, b1 = min(B, b0 + CH);
  int tt = 0;
  for (int b = b0; b < b1; b++) tt += btot[b];
  partial[t] = tt;
  __syncthreads();
  if (t == 0) {
    int acc = 0;
    for (int i = 0; i < 256; i++) { int v = partial[i]; partial[i] = acc; acc += v; }
  }
  __syncthreads();
  int off = partial[t];
  for (int b = b0; b < b1; b++) { boff[b] = off; off += btot[b]; }
  if (t == 255) boff[B] = E;
}

// record = (dst_local << 17) | src   (needs N <= 131072)
__global__ __launch_bounds__(256) void k_bfill(const int* __restrict__ src,
                                               const int* __restrict__ dst,
                                               const int* __restrict__ hist,
                                               const int* __restrict__ boff,
                                               int* __restrict__ buck,
                                               int E, int B, int chunk) {
  __shared__ int cur[MAXB];
  int w = blockIdx.x, tid = threadIdx.x;
  for (int b = tid; b < B; b += 256) cur[b] = boff[b] + hist[w * B + b];
  __syncthreads();
  int e0 = w * chunk, e1 = min(E, e0 + chunk);
  for (int e = e0 + tid; e < e1; e += 256) {
    int d = dst[e];
    int b = d >> 6, dl = d & 63;
    int p = atomicAdd(&cur[b], 1);
    buck[p] = (dl << 17) | src[e];
  }
}

// ---------------- per-bucket counting sort -> exact per-node CSR ----------------
__global__ __launch_bounds__(256) void k_bsort(const int* __restrict__ buck,
                                               const int* __restrict__ boff,
                                               int* __restrict__ csr,
                                               int* __restrict__ noff,
                                               float* __restrict__ dinv, int N) {
  __shared__ int bin[NB];
  __shared__ int excl[NB];
  int b = blockIdx.x, tid = threadIdx.x;
  if (tid < NB) bin[tid] = 0;
  __syncthreads();
  int r0 = boff[b], r1 = boff[b + 1];
  for (int r = r0 + tid; r < r1; r += 256) atomicAdd(&bin[buck[r] >> 17], 1);
  __syncthreads();
  if (tid == 0) {
    int acc = 0;
    for (int i = 0; i < NB; i++) { excl[i] = acc; acc += bin[i]; }
  }
  __syncthreads();
  if (tid < NB) {
    int n = b * NB + tid;
    if (n < N) {
      dinv[n] = rsqrtf((float)bin[tid] + 1.0f);  // +1 self-loop
      noff[n] = r0 + excl[tid];
    }
  }
  if (b == gridDim.x - 1 && tid == 128) noff[N] = r1;  // r1 == E for last bucket
  __syncthreads();
  if (tid < NB) bin[tid] = excl[tid];  // reuse as cursors
  __syncthreads();
  for (int r = r0 + tid; r < r1; r += 256) {
    int rec = buck[r];
    int p = atomicAdd(&bin[rec >> 17], 1);
    csr[r0 + p] = rec & 0x1FFFF;
  }
}

// ============ MFMA GEMMs (mfma_f32_16x16x32_f16), all inputs fp16 ============
// A-frag:  A[m = lane&15][k = (lane>>4)*8 + j]
// D:       D[row = (lane>>4)*4 + reg][col = lane&15]

// ---------------- GEMM1: G = fp16((Xh @ W1) * dinv[row])   (Xh fp16 N x 128) ----------------
__global__ __launch_bounds__(256, 4) void k_gemm1(const unsigned short* __restrict__ Xh,
                                                  const unsigned short* __restrict__ fW1,
                                                  const float* __restrict__ dinv,
                                                  unsigned short* __restrict__ G, int N) {
  int tid = threadIdx.x;
  const int lane = tid & 63, wave = tid >> 6;
  const int m = lane & 15, q = lane >> 4;
  half8 bfrag[4][4];
#pragma unroll
  for (int c = 0; c < 4; c++)
#pragma unroll
    for (int t = 0; t < 4; t++)
      bfrag[c][t] = *reinterpret_cast<const half8*>(fW1 + ((c * 4 + t) * 64 + lane) * 8);
  int ntiles = (N + 15) >> 4;
  for (int tile = blockIdx.x * 4 + wave; tile < ntiles; tile += gridDim.x * 4) {
    int r0 = tile << 4;
    int rm = r0 + m; rm = rm < N ? rm : N - 1;
    floatx4 acc[4] = {{0.f,0.f,0.f,0.f},{0.f,0.f,0.f,0.f},{0.f,0.f,0.f,0.f},{0.f,0.f,0.f,0.f}};
#pragma unroll
    for (int c = 0; c < 4; c++) {
      half8 a = *reinterpret_cast<const half8*>(Xh + (size_t)rm * F_IN + c * 32 + q * 8);
#pragma unroll
      for (int t = 0; t < 4; t++)
        acc[t] = __builtin_amdgcn_mfma_f32_16x16x32_f16(a, bfrag[c][t], acc[t], 0, 0, 0);
    }
#pragma unroll
    for (int rr = 0; rr < 4; rr++) {
      int grow = r0 + q * 4 + rr;
      if (grow < N) {
        float dv = dinv[grow];
#pragma unroll
        for (int t = 0; t < 4; t++)
          G[(size_t)grow * F_HID + t * 16 + m] = f2h(acc[t][rr] * dv);
      }
    }
  }
}

// ---------------- GEMM2: G = fp16((O @ W2) * dinv[row])   (O fp16) ----------------
__global__ __launch_bounds__(256, 4) void k_gemm2(const unsigned short* __restrict__ O,
                                                  const unsigned short* __restrict__ fW2,
                                                  const float* __restrict__ dinv,
                                                  unsigned short* __restrict__ G, int N) {
  int tid = threadIdx.x;
  const int lane = tid & 63, wave = tid >> 6;
  const int m = lane & 15, q = lane >> 4;
  half8 bfrag[2][4];
#pragma unroll
  for (int c = 0; c < 2; c++)
#pragma unroll
    for (int t = 0; t < 4; t++)
      bfrag[c][t] = *reinterpret_cast<const half8*>(fW2 + ((c * 4 + t) * 64 + lane) * 8);
  int ntiles = (N + 15) >> 4;
  for (int tile = blockIdx.x * 4 + wave; tile < ntiles; tile += gridDim.x * 4) {
    int r0 = tile << 4;
    int rm = r0 + m; rm = rm < N ? rm : N - 1;
    floatx4 acc[4] = {{0.f,0.f,0.f,0.f},{0.f,0.f,0.f,0.f},{0.f,0.f,0.f,0.f},{0.f,0.f,0.f,0.f}};
#pragma unroll
    for (int c = 0; c < 2; c++) {
      half8 a = *reinterpret_cast<const half8*>(O + (size_t)rm * F_HID + c * 32 + q * 8);
#pragma unroll
      for (int t = 0; t < 4; t++)
        acc[t] = __builtin_amdgcn_mfma_f32_16x16x32_f16(a, bfrag[c][t], acc[t], 0, 0, 0);
    }
#pragma unroll
    for (int rr = 0; rr < 4; rr++) {
      int grow = r0 + q * 4 + rr;
      if (grow < N) {
        float dv = dinv[grow];
#pragma unroll
        for (int t = 0; t < 4; t++)
          G[(size_t)grow * F_HID + t * 16 + m] = f2h(acc[t][rr] * dv);
      }
    }
  }
}

// ---------------- aggregate (exact CSR, register accumulation, fp16 rows) + fused epilogue ----------------
template <bool RELU>
__global__ __launch_bounds__(256) void k_agg(const int* __restrict__ csr,
                                             const int* __restrict__ noff,
                                             const unsigned short* __restrict__ H,
                                             const float* __restrict__ dinv,
                                             const void* __restrict__ bias,
                                             unsigned short* __restrict__ OUT, int N,
                                             const int* __restrict__ flagp) {
  const bool isb = (*flagp != 0);
  int lane = threadIdx.x & 63;
  int gw = (blockIdx.x * 256 + threadIdx.x) >> 6;
  int nW = (gridDim.x * 256) >> 6;
  float bv = isb ? bf2f(((const unsigned short*)bias)[lane])
                 : ((const float*)bias)[lane];
  for (int n = gw; n < N; n += nW) {
    int start = noff[n], end = noff[n + 1];
    float acc0 = 0.f, acc1 = 0.f;
    for (int e0 = start; e0 < end; e0 += 64) {
      int ee = e0 + lane;
      int idx = (ee < end) ? csr[ee] : 0;
      int m = end - e0; m = m < 64 ? m : 64;
      int k = 0;
      for (; k + 3 < m; k += 4) {
        int s0 = __shfl(idx, k, 64);
        int s1 = __shfl(idx, k + 1, 64);
        int s2 = __shfl(idx, k + 2, 64);
        int s3 = __shfl(idx, k + 3, 64);
        float v0 = h2f(H[(size_t)s0 * F_HID + lane]);
        float v1 = h2f(H[(size_t)s1 * F_HID + lane]);
        float v2 = h2f(H[(size_t)s2 * F_HID + lane]);
        float v3 = h2f(H[(size_t)s3 * F_HID + lane]);
        acc0 += v0 + v2;
        acc1 += v1 + v3;
      }
      for (; k < m; k++) {
        int s0 = __shfl(idx, k, 64);
        acc0 += h2f(H[(size_t)s0 * F_HID + lane]);
      }
    }
    float self = h2f(H[(size_t)n * F_HID + lane]);  // self-loop (already * dinv[n])
    float o = (acc0 + acc1 + self) * dinv[n] + bv;
    if (RELU) o = fmaxf(o, 0.f);
    OUT[(size_t)n * F_HID + lane] = f2h(o);
  }
}

// ---------------- PR GEMM (MFMA): PR[n][0:128]=O[n]@Wa ; [128:256]=O[n]@Wb, fp16 out ----
__global__ __launch_bounds__(256, 4) void k_gemm_pr(const unsigned short* __restrict__ O,
                                                    const unsigned short* __restrict__ fPR,
                                                    unsigned short* __restrict__ PR, int N) {
  const int g = blockIdx.x & 3;
  int tid = threadIdx.x;
  const int lane = tid & 63, wave = tid >> 6;
  const int m = lane & 15, q = lane >> 4;
  const unsigned short* fW = fPR + g * 4096;
  half8 bfrag[2][4];
#pragma unroll
  for (int c = 0; c < 2; c++)
#pragma unroll
    for (int t = 0; t < 4; t++)
      bfrag[c][t] = *reinterpret_cast<const half8*>(fW + ((c * 4 + t) * 64 + lane) * 8);
  int ntiles = (N + 15) >> 4;
  int tstride = (gridDim.x >> 2) * 4;
  for (int tile = (blockIdx.x >> 2) * 4 + wave; tile < ntiles; tile += tstride) {
    int r0 = tile << 4;
    int rm = r0 + m; rm = rm < N ? rm : N - 1;
    floatx4 acc[4] = {{0.f,0.f,0.f,0.f},{0.f,0.f,0.f,0.f},{0.f,0.f,0.f,0.f},{0.f,0.f,0.f,0.f}};
#pragma unroll
    for (int c = 0; c < 2; c++) {
      half8 a = *reinterpret_cast<const half8*>(O + (size_t)rm * F_HID + c * 32 + q * 8);
#pragma unroll
      for (int t = 0; t < 4; t++)
        acc[t] = __builtin_amdgcn_mfma_f32_16x16x32_f16(a, bfrag[c][t], acc[t], 0, 0, 0);
    }
#pragma unroll
    for (int rr = 0; rr < 4; rr++) {
      int grow = r0 + q * 4 + rr;
      if (grow < N) {
#pragma unroll
        for (int t = 0; t < 4; t++)
          PR[(size_t)grow * 256 + g * 64 + t * 16 + m] = f2h(acc[t][rr]);
      }
    }
  }
}

// ---------------- query: out[q] = relu(P[i[q]] + R[j[q]] + fc1_b) @ fc2_W + fc2_b ----------------
__global__ __launch_bounds__(256) void k_query(const unsigned short* __restrict__ PRu,
                                               const int* __restrict__ qi,
                                               const int* __restrict__ qj,
                                               const void* __restrict__ fc1b,
                                               const void* __restrict__ fc2W,
                                               const void* __restrict__ fc2b,
                                               void* __restrict__ out, int Q,
                                               const int* __restrict__ flagp) {
  const bool isb = (*flagp != 0);
  int tid = threadIdx.x;
  int lane = tid & 63;
  int wave = tid >> 6;
  int g = lane >> 4, m = lane & 15;
  float bb[8], w0[8], w1[8];
#pragma unroll
  for (int t = 0; t < 8; t++) {
    int h = m * 8 + t;
    if (isb) {
      bb[t] = bf2f(((const unsigned short*)fc1b)[h]);
      w0[t] = bf2f(((const unsigned short*)fc2W)[h * 2 + 0]);
      w1[t] = bf2f(((const unsigned short*)fc2W)[h * 2 + 1]);
    } else {
      bb[t] = ((const float*)fc1b)[h];
      w0[t] = ((const float*)fc2W)[h * 2 + 0];
      w1[t] = ((const float*)fc2W)[h * 2 + 1];
    }
  }
  float ob0 = isb ? bf2f(((const unsigned short*)fc2b)[0]) : ((const float*)fc2b)[0];
  float ob1 = isb ? bf2f(((const unsigned short*)fc2b)[1]) : ((const float*)fc2b)[1];
  int gw = blockIdx.x * 4 + wave;
  int nW = gridDim.x * 4;
  int nQuad = (Q + 3) >> 2;
  for (int quad = gw; quad < nQuad; quad += nW) {
    int q = quad * 4 + g;
    int qq = q < Q ? q : Q - 1;
    int iq = qi[qq], jq = qj[qq];
    const ushort4* Pr = reinterpret_cast<const ushort4*>(PRu + (size_t)iq * 256) + m * 2;
    const ushort4* Rr = reinterpret_cast<const ushort4*>(PRu + (size_t)jq * 256 + 128) + m * 2;
    ushort4 pa = Pr[0], pb = Pr[1];
    ushort4 ra = Rr[0], rb = Rr[1];
    float h[8] = {h2f(pa.x) + h2f(ra.x), h2f(pa.y) + h2f(ra.y),
                  h2f(pa.z) + h2f(ra.z), h2f(pa.w) + h2f(ra.w),
                  h2f(pb.x) + h2f(rb.x), h2f(pb.y) + h2f(rb.y),
                  h2f(pb.z) + h2f(rb.z), h2f(pb.w) + h2f(rb.w)};
    float r0 = 0.f, r1 = 0.f;
#pragma unroll
    for (int t = 0; t < 8; t++) {
      float hv = fmaxf(h[t] + bb[t], 0.f);
      r0 += hv * w0[t];
      r1 += hv * w1[t];
    }
#pragma unroll
    for (int off = 8; off > 0; off >>= 1) {
      r0 += __shfl_xor(r0, off, 16);
      r1 += __shfl_xor(r1, off, 16);
    }
    if (m == 0 && q < Q) {
      if (isb) {
        *reinterpret_cast<ushort2*>((unsigned short*)out + (size_t)q * 2) =
            make_ushort2(f2bf(r0 + ob0), f2bf(r1 + ob1));
      } else {
        *reinterpret_cast<float2*>((float*)out + (size_t)q * 2) =
            make_float2(r0 + ob0, r1 + ob1);
      }
    }
  }
}

extern "C" void kernel_launch(void* const* d_in, const int* in_sizes, int n_in,
                              void* d_out, int out_size, void* d_ws, size_t ws_size,
                              hipStream_t stream) {
  const void* X    = d_in[0];
  const int*  edges= (const int*)d_in[1];
  const int*  qi   = (const int*)d_in[2];
  const int*  qj   = (const int*)d_in[3];
  const void* W1   = d_in[4];
  const void* b1   = d_in[5];
  const void* W2   = d_in[6];
  const void* b2   = d_in[7];
  const void* fc1W = d_in[8];
  const void* fc1b = d_in[9];
  const void* fc2W = d_in[10];
  const void* fc2b = d_in[11];

  const int N = in_sizes[0] / F_IN;
  const int E = in_sizes[1] / 2;
  const int Q = in_sizes[2];
  const int B = (N + NB - 1) / NB;           // buckets (<= MAXB for N <= 131072)
  const int chunk = (E + NWG - 1) / NWG;

  char* ws = (char*)d_ws;
  size_t off = 0;
  auto alloc = [&](size_t bytes) -> void* {
    void* p = ws + off;
    off += (bytes + 255) & ~(size_t)255;
    return p;
  };
  int*            flag = (int*)alloc(4);
  float*          dinv = (float*)alloc((size_t)N * 4);
  unsigned short* Xh   = (unsigned short*)alloc((size_t)N * F_IN * 2);   // fp16 X
  unsigned short* G    = (unsigned short*)alloc((size_t)N * F_HID * 2);  // gemm out (fp16)
  unsigned short* O    = (unsigned short*)alloc((size_t)N * F_HID * 2);  // layer out (fp16)
  unsigned short* fW1  = (unsigned short*)alloc((size_t)F_IN * F_HID * 2);   // frag-order fp16
  unsigned short* fW2  = (unsigned short*)alloc((size_t)F_HID * F_HID * 2);
  unsigned short* fPR  = (unsigned short*)alloc((size_t)4 * F_HID * 64 * 2);
  unsigned short* PR   = (unsigned short*)alloc((size_t)N * 256 * 2);    // [P | R] fp16
  // bucket/CSR scratch aliases PR (all reads precede gemm_pr's PR writes)
  char* scr = (char*)PR;
  size_t soff = 0;
  auto salloc = [&](size_t bytes) -> void* {
    void* p = scr + soff;
    soff += (bytes + 255) & ~(size_t)255;
    return p;
  };
  int* hist = (int*)salloc((size_t)NWG * B * 4);
  int* btot = (int*)salloc((size_t)(B + 1) * 4);
  int* boff = (int*)salloc((size_t)(B + 1) * 4);
  int* buck = (int*)salloc((size_t)E * 4);
  int* csr  = (int*)salloc((size_t)E * 4);
  int* noff = (int*)salloc((size_t)(N + 1) * 4);
  (void)ws_size; (void)n_in; (void)out_size;

  const int* esrc = edges;
  const int* edst = edges + E;

  k_detect<<<1, 64, 0, stream>>>((const unsigned int*)X, flag);
  k_xcast<<<2048, 256, 0, stream>>>(X, Xh, N * F_IN / 8, flag);
  k_prep<<<16, 256, 0, stream>>>(W1, W2, fc1W, fW1, fW2, fPR, flag);

  // bucket build + per-bucket counting sort -> exact CSR + noff + dinv
  k_bhist<<<NWG, 256, 0, stream>>>(edst, hist, E, B, chunk);
  k_bscan1<<<(B + 255) / 256, 256, 0, stream>>>(hist, btot, B);
  k_bscan2<<<1, 256, 0, stream>>>(btot, boff, B, E);
  k_bfill<<<NWG, 256, 0, stream>>>(esrc, edst, hist, boff, buck, E, B, chunk);
  k_bsort<<<B, 256, 0, stream>>>(buck, boff, csr, noff, dinv, N);

  // layer 1
  k_gemm1<<<2048, 256, 0, stream>>>(Xh, fW1, dinv, G, N);
  k_agg<true><<<2048, 256, 0, stream>>>(csr, noff, G, dinv, b1, O, N, flag);

  // layer 2
  k_gemm2<<<2048, 256, 0, stream>>>(O, fW2, dinv, G, N);
  k_agg<false><<<2048, 256, 0, stream>>>(csr, noff, G, dinv, b2, O, N, flag);

  // MLP factorization: PR = out2 @ [Wa | Wb]  (overwrites bucket scratch — safe)
  k_gemm_pr<<<2048, 256, 0, stream>>>(O, fPR, PR, N);

  // per-query: gather P[i] + R[j], relu, fc2
  k_query<<<4096, 256, 0, stream>>>(PR, qi, qj, fc1b, fc2W, fc2b, d_out, Q, flag);
}